// Round 4
// baseline (973.496 us; speedup 1.0000x reference)
//
#include <hip/hip_runtime.h>
#include <hip/hip_bf16.h>

// TreeNet: T=512 nodes, B=256 batch, D=256 dim, BF=2 branching.
// Decomposition:
//   K0  stack simulation (int only) -> child lists / worklists
//   K1  H = inputs @ W_in + b; leaf rows (ar<=0) get tanh fused at store
//       (R4: 128x256 block tile, 8x16 thread tile -> 0.75 B LDS per FMA)
//   K2a G[t] += H[leaf_child] @ W_ch[i]  (frozen 8x8-tile control for A/B vs K1)
//   K3  sequential per-batch chain; R4: TC=8 cols x P=16 slices
//       (h-delivery 64->32 b128/step), bank-padded partial[16][260],
//       worklist in LDS, root gather folded into tail.
//   (k_root folded into K3)

constexpr int T = 512, B = 256, D = 256;

typedef float f2 __attribute__((ext_vector_type(2)));
typedef float f4 __attribute__((ext_vector_type(4)));

// ws layout in u32 units
constexpr int WS_CNT  = 0;        // [2] atomic counters for leaf lists
constexpr int WS_ROOT = 16;       // [256]
constexpr int WS_NW   = 272;      // [256]
constexpr int WS_L0   = 1024;     // [131072] leaf-child entries, i=0
constexpr int WS_L1   = WS_L0 + T * B;     // [131072] i=1
constexpr int WS_WORK = WS_L1 + T * B;     // [256*1024] per-k combine worklist

// ---------------- K0: stack simulation ----------------
__global__ __launch_bounds__(256) void k_stack(const int* __restrict__ ar,
                                               unsigned* __restrict__ ws) {
  __shared__ int ar_l[T];
  __shared__ int S[1024];          // stack ring buffer (mask 1023), write-through
  __shared__ unsigned lbuf0[T];
  __shared__ unsigned lbuf1[T];
  __shared__ unsigned wbuf[1024];
  __shared__ int cnts[4];          // n0, n1, nw, root
  __shared__ unsigned base0, base1;

  int k = blockIdx.x;
  int tid = threadIdx.x;
  ar_l[tid]       = ar[tid * B + k];
  ar_l[tid + 256] = ar[(tid + 256) * B + k];
  S[tid] = 0; S[tid + 256] = 0; S[tid + 512] = 0; S[tid + 768] = 0;
  __syncthreads();

  if (tid == 0) {
    int ptr = 1;           // BF-1
    int top = 0, next = 0; // register cache of S[ptr], S[ptr-1]
    int n0 = 0, n1 = 0, nw = 0;
    for (int t = 0; t < T; t++) {
      int a = ar_l[t];
      int aa = a < 0 ? -a : a;
      unsigned cc[2]; int ncc = 0;
      if (a > 0) {
        int c0 = top;
        if (ar_l[c0] <= 0)
          lbuf0[n0++] = (unsigned)c0 | ((unsigned)t << 9) | ((unsigned)k << 18);
        else
          cc[ncc++] = (unsigned)c0;                 // child slot 0 -> W_ch[0]
        if (a > 1) {
          int c1 = next;
          if (ar_l[c1] <= 0)
            lbuf1[n1++] = (unsigned)c1 | ((unsigned)t << 9) | ((unsigned)k << 18);
          else
            cc[ncc++] = (unsigned)c1 | (1u << 18);  // child slot 1 -> W_ch[1]
        }
      }
      if (a >= 1) {  // combine node: K3 must finalize (tanh) it
        if (ncc == 0) {
          wbuf[nw++] = (unsigned)t | (1u << 19) | (1u << 20);
        } else {
          for (int e = 0; e < ncc; e++) {
            unsigned w = (unsigned)t | ((cc[e] & 511u) << 9) |
                         (((cc[e] >> 18) & 1u) << 18) | (1u << 21);
            if (e == 0) w |= (1u << 19);
            if (e == ncc - 1) w |= (1u << 20);
            wbuf[nw++] = w;
          }
        }
      }
      int pnew = ptr - aa + 1;
      if (a != -1) {
        S[pnew & 1023] = t;                 // write-through
        if (aa == 0)      { next = top; top = t; }
        else if (aa == 1) { top = t; }
        else              { top = t; next = S[(pnew - 1) & 1023]; } // refill
      }
      ptr = pnew;
    }
    cnts[0] = n0; cnts[1] = n1; cnts[2] = nw;
    cnts[3] = S[ptr & 1023];
    base0 = atomicAdd(ws + WS_CNT + 0, (unsigned)n0);
    base1 = atomicAdd(ws + WS_CNT + 1, (unsigned)n1);
  }
  __syncthreads();
  int n0 = cnts[0], n1 = cnts[1], nw = cnts[2];
  for (int i = tid; i < n0; i += 256) ws[WS_L0 + base0 + i] = lbuf0[i];
  for (int i = tid; i < n1; i += 256) ws[WS_L1 + base1 + i] = lbuf1[i];
  for (int i = tid; i < nw; i += 256) ws[WS_WORK + k * 1024 + i] = wbuf[i];
  if (tid == 0) { ws[WS_NW + k] = (unsigned)nw; ws[WS_ROOT + k] = (unsigned)cnts[3]; }
}

// ---------------- K1: H = X @ W_in + b  (+ fused leaf tanh) ----------------
// R4: 128-row x 256-col block tile, 256 threads, 8x16 per-thread tile.
// LDS bytes per FMA: (8+16)*4/128 = 0.75 (was 1.0 at 8x8).
// Per-element k-summation order unchanged -> H bitwise identical to R2/R3.
__global__ __launch_bounds__(256) void k_gemm_h(const float* __restrict__ X,
                                                const float* __restrict__ W,
                                                const float* __restrict__ bias,
                                                const int* __restrict__ ar,
                                                float* __restrict__ Hm) {
  int row0 = blockIdx.x * 128;
  __shared__ __align__(16) float As[16][132];  // [k][row], stride%32=4
  __shared__ __align__(16) float Bs[16][256];  // [k][col]
  __shared__ int lar[128];
  int tid = threadIdx.x;
  if (tid < 128) lar[tid] = ar[row0 + tid];    // row = t*B+k == flat ar index
  int cg = tid & 15;        // cols: 64*qt + cg*4 + q, qt=0..3
  int rg = tid >> 4;        // rows: rg*8 .. rg*8+8
  float acc[8][16];
  f4 bv[4];
#pragma unroll
  for (int qt = 0; qt < 4; qt++) bv[qt] = *(const f4*)&bias[64 * qt + cg * 4];
#pragma unroll
  for (int rr = 0; rr < 8; rr++)
#pragma unroll
    for (int qt = 0; qt < 4; qt++) {
      acc[rr][4 * qt + 0] = bv[qt].x; acc[rr][4 * qt + 1] = bv[qt].y;
      acc[rr][4 * qt + 2] = bv[qt].z; acc[rr][4 * qt + 3] = bv[qt].w;
    }
  int sr = tid >> 1;            // staging row 0..127
  int skc = (tid & 1) * 8;      // staging k-offset 0 or 8
  for (int kk = 0; kk < 256; kk += 16) {
    f4 xa = *(const f4*)&X[(row0 + sr) * 256 + kk + skc];
    f4 xb = *(const f4*)&X[(row0 + sr) * 256 + kk + skc + 4];
    As[skc + 0][sr] = xa.x; As[skc + 1][sr] = xa.y;
    As[skc + 2][sr] = xa.z; As[skc + 3][sr] = xa.w;
    As[skc + 4][sr] = xb.x; As[skc + 5][sr] = xb.y;
    As[skc + 6][sr] = xb.z; As[skc + 7][sr] = xb.w;
#pragma unroll
    for (int i = 0; i < 4; i++) {
      int idx = tid + i * 256;
      int r = idx >> 6, c4 = idx & 63;
      *(f4*)&Bs[r][c4 * 4] = *(const f4*)&W[(kk + r) * 256 + c4 * 4];
    }
    __syncthreads();
#pragma unroll
    for (int kc = 0; kc < 16; kc++) {
      f4 A0 = *(const f4*)&As[kc][rg * 8];
      f4 A1 = *(const f4*)&As[kc][rg * 8 + 4];
      f4 B0 = *(const f4*)&Bs[kc][cg * 4];
      f4 B1 = *(const f4*)&Bs[kc][64 + cg * 4];
      f4 B2 = *(const f4*)&Bs[kc][128 + cg * 4];
      f4 B3 = *(const f4*)&Bs[kc][192 + cg * 4];
      float a[8]  = {A0.x, A0.y, A0.z, A0.w, A1.x, A1.y, A1.z, A1.w};
      float b[16] = {B0.x, B0.y, B0.z, B0.w, B1.x, B1.y, B1.z, B1.w,
                     B2.x, B2.y, B2.z, B2.w, B3.x, B3.y, B3.z, B3.w};
#pragma unroll
      for (int rr = 0; rr < 8; rr++)
#pragma unroll
        for (int q = 0; q < 16; q++) acc[rr][q] += a[rr] * b[q];
    }
    __syncthreads();
  }
#pragma unroll
  for (int rr = 0; rr < 8; rr++) {
    int row = rg * 8 + rr;
    bool leaf = lar[row] <= 0;   // leaf (or ignore) node: finalize with tanh
    float* dst = &Hm[(row0 + row) * 256];
#pragma unroll
    for (int qt = 0; qt < 4; qt++) {
      f4 v;
      v.x = acc[rr][4 * qt + 0]; v.y = acc[rr][4 * qt + 1];
      v.z = acc[rr][4 * qt + 2]; v.w = acc[rr][4 * qt + 3];
      if (leaf) { v.x = tanhf(v.x); v.y = tanhf(v.y);
                  v.z = tanhf(v.z); v.w = tanhf(v.w); }
      *(f4*)&dst[64 * qt + cg * 4] = v;
    }
  }
}

// ---------------- K2a: gather-GEMM of leaf-child contributions ----------------
// (frozen from R2/R3 -- serves as the 8x8-tile control vs K1's new 8x16)
__global__ __launch_bounds__(256) void k_leafgemm(const float* __restrict__ Hm,
                                                  float* __restrict__ Gm,
                                                  const float* __restrict__ Wch,
                                                  const unsigned* __restrict__ list,
                                                  const unsigned* __restrict__ cntp,
                                                  int which) {
  unsigned cnt = *cntp;
  unsigned tile0 = blockIdx.x * 64;
  if (tile0 >= cnt) return;
  int ne = (int)min(64u, cnt - tile0);
  __shared__ unsigned ent[64];
  __shared__ __align__(16) float As[16][68];
  __shared__ __align__(16) float Bs[16][256];
  int tid = threadIdx.x;
  if (tid < 64) ent[tid] = (tid < ne) ? list[tile0 + tid] : 0u;
  __syncthreads();
  const float* W = Wch + which * (D * D);
  int cq = tid & 31, rg = tid >> 5;
  float acc[8][8];
#pragma unroll
  for (int rr = 0; rr < 8; rr++)
#pragma unroll
    for (int q = 0; q < 8; q++) acc[rr][q] = 0.0f;
  int sr = tid >> 2;
  int skc = (tid & 3) * 4;
  unsigned se = ent[sr];
  int sc = (int)(se & 511u), skb = (int)((se >> 18) & 255u);
  const float* srow = &Hm[((sc << 8) + skb) * 256];
  for (int kk = 0; kk < 256; kk += 16) {
    float4 a4;
    if (sr < ne) a4 = *(const float4*)&srow[kk + skc];
    else { a4.x = a4.y = a4.z = a4.w = 0.0f; }
    As[skc + 0][sr] = a4.x; As[skc + 1][sr] = a4.y;
    As[skc + 2][sr] = a4.z; As[skc + 3][sr] = a4.w;
#pragma unroll
    for (int i = 0; i < 4; i++) {
      int idx = tid + i * 256;
      int r = idx >> 6, c4 = idx & 63;
      *(float4*)&Bs[r][c4 * 4] = *(const float4*)&W[(kk + r) * 256 + c4 * 4];
    }
    __syncthreads();
#pragma unroll
    for (int kc = 0; kc < 16; kc++) {
      float4 a0  = *(const float4*)&As[kc][rg * 8];
      float4 a1  = *(const float4*)&As[kc][rg * 8 + 4];
      float4 blo = *(const float4*)&Bs[kc][cq * 4];
      float4 bhi = *(const float4*)&Bs[kc][128 + cq * 4];
      float a[8]  = {a0.x, a0.y, a0.z, a0.w, a1.x, a1.y, a1.z, a1.w};
      float bb[8] = {blo.x, blo.y, blo.z, blo.w, bhi.x, bhi.y, bhi.z, bhi.w};
#pragma unroll
      for (int rr = 0; rr < 8; rr++)
#pragma unroll
        for (int q = 0; q < 8; q++) acc[rr][q] += a[rr] * bb[q];
    }
    __syncthreads();
  }
#pragma unroll
  for (int rr = 0; rr < 8; rr++) {
    int e = rg * 8 + rr;
    if (e < ne) {
      unsigned en = ent[e];
      int t = (int)((en >> 9) & 511u), kb = (int)((en >> 18) & 255u);
      float* dst = &Gm[((t << 8) + kb) * 256];
      float4 lo = *(const float4*)&dst[cq * 4];
      float4 hi = *(const float4*)&dst[128 + cq * 4];
      lo.x += acc[rr][0]; lo.y += acc[rr][1]; lo.z += acc[rr][2]; lo.w += acc[rr][3];
      hi.x += acc[rr][4]; hi.y += acc[rr][5]; hi.z += acc[rr][6]; hi.w += acc[rr][7];
      *(float4*)&dst[cq * 4] = lo;
      *(float4*)&dst[128 + cq * 4] = hi;
    }
  }
}

// ---------------- K3: sequential combine chain, one wg per batch ----------------
// R4 layout: thread (cs = tid&31, ps = tid>>5): cols [8cs, 8cs+8) x p-slice
// [16ps, 16ps+16). h-delivery: 4 b128 broadcast reads/thread = 32 instrs/step
// (was 64). partial[16][260]: +4 pad -> even/odd ps cover all 32 banks on the
// 2 contiguous b128 partial writes. Worklist staged in LDS. W_ch[1] fragment
// (64 f2 = 128 regs) pinned via empty asm. Root gather folded into the tail.
__global__ __launch_bounds__(512, 2) void k_seq(float* __restrict__ Mm,
                                                float* __restrict__ out,
                                                const float* __restrict__ Wch,
                                                const unsigned* __restrict__ ws) {
  int k = blockIdx.x;
  int tid = threadIdx.x;
  int cs = tid & 31;          // col-group: cols [8cs, 8cs+8)
  int ps = tid >> 5;          // p-slice:  [16ps, 16ps+16)
  __shared__ __align__(16) float crow[2][256];     // double-buffered h vector
  __shared__ __align__(16) float partial[16][260]; // per-slice partials, padded
  __shared__ unsigned wlds[1024];
  // W_ch[1] rows [16ps..+16), cols [8cs..+8) -> 64 f2 = 128 VGPRs
  f2 wa[64];
  const float* W1 = Wch + D * D;
#pragma unroll
  for (int p = 0; p < 16; p++) {
    f4 w0 = *(const f4*)&W1[(16 * ps + p) * 256 + 8 * cs];
    f4 w1 = *(const f4*)&W1[(16 * ps + p) * 256 + 8 * cs + 4];
    wa[4 * p + 0] = __builtin_shufflevector(w0, w0, 0, 1);
    wa[4 * p + 1] = __builtin_shufflevector(w0, w0, 2, 3);
    wa[4 * p + 2] = __builtin_shufflevector(w1, w1, 0, 1);
    wa[4 * p + 3] = __builtin_shufflevector(w1, w1, 2, 3);
  }
#pragma unroll
  for (int q = 0; q < 64; q++) asm volatile("" : "+v"(wa[q]));
  int nw = (int)ws[WS_NW + k];
  const unsigned* work = ws + WS_WORK + k * 1024;
  for (int i = tid; i < nw; i += 512) wlds[i] = work[i];
  int cached = -1, rb = 0;
  __syncthreads();
  unsigned e = (nw > 0) ? wlds[0] : 0u;
  float nb = 0.0f;    // prefetched G-row value for the next `first` entry
  if (nw > 0 && ((e >> 19) & 1u) && tid < 256)
    nb = Mm[(((int)(e & 511u) << 8) + k) * 256 + tid];
  float gval = 0.0f;  // G-row value latched at `first`, used at `last`
  f2 a0 = {0.f, 0.f}, a1 = {0.f, 0.f}, a2 = {0.f, 0.f}, a3 = {0.f, 0.f};
  for (int n = 0; n < nw; n++) {
    unsigned cur = e;
    unsigned nxt = (n + 1 < nw) ? wlds[n + 1] : 0u;
    int t = (int)(cur & 511u), c = (int)((cur >> 9) & 511u);
    int wi = (int)((cur >> 18) & 1u);
    bool first = (cur >> 19) & 1u, last = (cur >> 20) & 1u, hasc = (cur >> 21) & 1u;
    if (first) {
      a0 = (f2){0.f, 0.f}; a1 = (f2){0.f, 0.f};
      a2 = (f2){0.f, 0.f}; a3 = (f2){0.f, 0.f};
      gval = nb;
    }
    float nb2 = 0.0f;                          // issue next prefetch early
    if ((n + 1 < nw) && ((nxt >> 19) & 1u) && tid < 256)
      nb2 = Mm[(((int)(nxt & 511u) << 8) + k) * 256 + tid];
    if (hasc) {
      if (c != cached) {
        // rare generic path: full drain so prior in-flight stores are visible
        asm volatile("s_waitcnt vmcnt(0) lgkmcnt(0)" ::: "memory");
        __builtin_amdgcn_s_barrier();
        __builtin_amdgcn_sched_barrier(0);
        if (tid < 256) crow[rb][tid] = Mm[((c << 8) + k) * 256 + tid];
        cached = c;
        asm volatile("s_waitcnt vmcnt(0) lgkmcnt(0)" ::: "memory");
        __builtin_amdgcn_s_barrier();
        __builtin_amdgcn_sched_barrier(0);
      }
      if (wi == 1) {  // fast path: register-resident W_ch[1] fragment
        const f4* hb = (const f4*)&crow[rb][16 * ps];
        f4 h0 = hb[0], h1 = hb[1], h2 = hb[2], h3 = hb[3];
        float hv[16];
        hv[0] = h0.x; hv[1] = h0.y; hv[2]  = h0.z; hv[3]  = h0.w;
        hv[4] = h1.x; hv[5] = h1.y; hv[6]  = h1.z; hv[7]  = h1.w;
        hv[8] = h2.x; hv[9] = h2.y; hv[10] = h2.z; hv[11] = h2.w;
        hv[12] = h3.x; hv[13] = h3.y; hv[14] = h3.z; hv[15] = h3.w;
#pragma unroll
        for (int p = 0; p < 16; p++) {
          f2 hp = {hv[p], hv[p]};
          a0 += hp * wa[4 * p + 0]; a1 += hp * wa[4 * p + 1];
          a2 += hp * wa[4 * p + 2]; a3 += hp * wa[4 * p + 3];
        }
      } else {        // rare: stream W_ch[0] from L2
        const float* W0 = Wch;
#pragma unroll 4
        for (int p = 0; p < 16; p++) {
          float hvv = crow[rb][16 * ps + p];
          f4 v0 = *(const f4*)&W0[(16 * ps + p) * 256 + 8 * cs];
          f4 v1 = *(const f4*)&W0[(16 * ps + p) * 256 + 8 * cs + 4];
          f2 hp = {hvv, hvv};
          a0 += hp * (f2){v0.x, v0.y}; a1 += hp * (f2){v0.z, v0.w};
          a2 += hp * (f2){v1.x, v1.y}; a3 += hp * (f2){v1.z, v1.w};
        }
      }
    }
    if (last) {
      f4 p0 = {a0.x, a0.y, a1.x, a1.y};
      f4 p1 = {a2.x, a2.y, a3.x, a3.y};
      *(f4*)&partial[ps][8 * cs]     = p0;
      *(f4*)&partial[ps][8 * cs + 4] = p1;
      __builtin_amdgcn_sched_barrier(0);
      asm volatile("s_waitcnt lgkmcnt(0)" ::: "memory");
      __builtin_amdgcn_s_barrier();        // partials visible (no vmcnt drain)
      __builtin_amdgcn_sched_barrier(0);
      if (tid < 256) {
        float s = gval;
#pragma unroll
        for (int m = 0; m < 16; m++) s += partial[m][tid];
        float v = tanhf(s);
        crow[rb ^ 1][tid] = v;              // write-side buffer
        Mm[((t << 8) + k) * 256 + tid] = v; // fire-and-forget store
      }
      __builtin_amdgcn_sched_barrier(0);
      asm volatile("s_waitcnt lgkmcnt(0)" ::: "memory");
      __builtin_amdgcn_s_barrier();        // crow visible (no vmcnt drain)
      __builtin_amdgcn_sched_barrier(0);
      rb ^= 1;
      cached = t;
    }
    e = nxt; nb = nb2;
  }
  // folded k_root: drain our Mm stores, then gather the root row
  asm volatile("s_waitcnt vmcnt(0) lgkmcnt(0)" ::: "memory");
  __builtin_amdgcn_s_barrier();
  unsigned r = ws[WS_ROOT + k];
  if (tid < 256)
    out[k * 256 + tid] = Mm[(((int)r << 8) + k) * 256 + tid];
}

extern "C" void kernel_launch(void* const* d_in, const int* in_sizes, int n_in,
                              void* d_out, int out_size, void* d_ws, size_t ws_size,
                              hipStream_t stream) {
  const float* X    = (const float*)d_in[0];
  const int*   AR   = (const int*)d_in[1];
  const float* Win  = (const float*)d_in[2];
  const float* Wch  = (const float*)d_in[3];
  const float* bias = (const float*)d_in[4];
  float* out = (float*)d_out;
  float* Mm  = out + B * D;  // memory region of output doubles as H/G scratch
  unsigned* ws = (unsigned*)d_ws;

  hipMemsetAsync(d_ws, 0, 512, stream);  // zero atomic counters
  k_stack<<<B, 256, 0, stream>>>(AR, ws);
  k_gemm_h<<<(T * B) / 128, 256, 0, stream>>>(X, Win, bias, AR, Mm);
  k_leafgemm<<<(T * B) / 64, 256, 0, stream>>>(Mm, Mm, Wch, ws + WS_L0, ws + WS_CNT + 0, 0);
  k_leafgemm<<<(T * B) / 64, 256, 0, stream>>>(Mm, Mm, Wch, ws + WS_L1, ws + WS_CNT + 1, 1);
  k_seq<<<B, 512, 0, stream>>>(Mm, out, Wch, ws);
}